// Round 1
// baseline (170.424 us; speedup 1.0000x reference)
//
#include <hip/hip_runtime.h>
#include <stdint.h>
#include <math.h>

// Problem constants (match reference)
#define B_N   32768
#define INDIM 256
#define HID   256
#define NE    8
#define KM1   4
#define KCLS  5
#define BM    64
#define PADN  (B_N + NE * BM)        // 33280: per-expert segments padded to 64
#define NBLK  (PADN / BM)            // 520

typedef __bf16 bf16x8 __attribute__((ext_vector_type(8)));
typedef float  f32x4  __attribute__((ext_vector_type(4)));
typedef unsigned short u16x8 __attribute__((ext_vector_type(8)));

__device__ __forceinline__ unsigned short f2bf(float f) {
    union { float f; unsigned u; } v; v.f = f;
    unsigned r = v.u + 0x7FFFu + ((v.u >> 16) & 1u);   // RNE
    return (unsigned short)(r >> 16);
}
__device__ __forceinline__ float bf2f(unsigned short b) {
    union { unsigned u; float f; } v; v.u = ((unsigned)b) << 16;
    return v.f;
}

// ---- prep: W1 [E][IN][HID] f32  ->  w1T [E][HID][IN] bf16 (transposed) ----
__global__ __launch_bounds__(256) void k_w1t(const float* __restrict__ W1,
                                             unsigned short* __restrict__ w1T) {
    __shared__ float tile[64][65];
    int b  = blockIdx.x;            // E*4*4 = 128 blocks
    int e  = b >> 4;
    int ti = (b >> 2) & 3;          // i (K) tile
    int th = b & 3;                 // h (N) tile
    const float* src = W1 + (((size_t)e * INDIM) + (size_t)ti * 64) * HID + th * 64;
    int col = threadIdx.x & 63;
    int r0  = (threadIdx.x >> 6) * 16;
    #pragma unroll
    for (int rr = 0; rr < 16; ++rr)
        tile[r0 + rr][col] = src[(size_t)(r0 + rr) * HID + col];
    __syncthreads();
    int hl = threadIdx.x >> 2;      // 0..63  (h within tile)
    int iq = threadIdx.x & 3;       // quarter of i range
    unsigned short* dst = w1T + (((size_t)e * HID) + th * 64 + hl) * INDIM + ti * 64 + iq * 16;
    #pragma unroll
    for (int s = 0; s < 16; ++s)
        dst[s] = f2bf(tile[iq * 16 + s][hl]);
}

// ---- prep: init perm = -1, hist = 0 ----
__global__ void k_init(int* __restrict__ perm, int* __restrict__ hist) {
    int i = blockIdx.x * 256 + threadIdx.x;
    if (i < PADN) perm[i] = -1;
    if (i < NE && blockIdx.x == 0) hist[i] = 0;
}

// ---- prep: histogram of experts ----
__global__ void k_hist(const int* __restrict__ sidx, int* __restrict__ hist) {
    __shared__ int lh[NE];
    if (threadIdx.x < NE) lh[threadIdx.x] = 0;
    __syncthreads();
    int i = blockIdx.x * 256 + threadIdx.x;
    if (i < B_N) atomicAdd(&lh[sidx[i]], 1);
    __syncthreads();
    if (threadIdx.x < NE) atomicAdd(&hist[threadIdx.x], lh[threadIdx.x]);
}

// ---- prep: exclusive scan with 64-row padding; init cursors ----
__global__ void k_scan(const int* __restrict__ hist, int* __restrict__ offs,
                       int* __restrict__ cursor) {
    if (threadIdx.x == 0) {
        int acc = 0;
        for (int e = 0; e < NE; ++e) {
            offs[e] = acc;
            cursor[e] = acc;
            acc += ((hist[e] + BM - 1) / BM) * BM;
        }
        offs[NE] = acc;
    }
}

// ---- prep: scatter sample ids into per-expert segments ----
__global__ void k_scatter(const int* __restrict__ sidx, int* __restrict__ cursor,
                          int* __restrict__ perm) {
    int i = blockIdx.x * 256 + threadIdx.x;
    if (i < B_N) {
        int e = sidx[i];
        int pos = atomicAdd(&cursor[e], 1);
        perm[pos] = i;
    }
}

__device__ __forceinline__ void gload_lds16(const void* g, void* l) {
    __builtin_amdgcn_global_load_lds(
        (__attribute__((address_space(1))) unsigned int*)(g),
        (__attribute__((address_space(3))) unsigned int*)(l),
        16, 0, 0);
}

// ---- main: fused grouped GEMM (bf16 MFMA) + bias/relu + layer2 + ordinal probs ----
__global__ __launch_bounds__(256) void k_main(
    const float* __restrict__ x,  const float* __restrict__ b1,
    const float* __restrict__ W2, const float* __restrict__ b2,
    const unsigned short* __restrict__ w1T,
    const int* __restrict__ perm, const int* __restrict__ offs,
    float* __restrict__ out)
{
    // xs: 64 rows x 256 bf16, 16B-chunk XOR-swizzled (chunk ^= row&7). 32KB.
    // Reused for h after the K loop.
    __shared__ unsigned short xs[BM * 256];
    // W1 K-slice staging, [n=256][k=32] bf16, double buffered. 2x16KB.
    __shared__ unsigned short w1s[2][256 * 32];

    int base = blockIdx.x * BM;
    if (base >= offs[NE]) return;
    int e = 0;
    #pragma unroll
    for (int t = 1; t < NE; ++t) if (base >= offs[t]) e = t;

    int tid  = threadIdx.x;
    int lane = tid & 63;
    int wave = tid >> 6;
    int r15  = lane & 15;
    int hi   = lane >> 4;

    // ---- stage gathered x rows -> LDS bf16 (swizzled) ----
    int row = tid >> 2;          // 0..63: local row
    int q   = tid & 3;           // quarter of the 256 cols
    int smp = perm[base + row];
    {
        const float* xr = x + (size_t)(smp < 0 ? 0 : smp) * INDIM + q * 64;
        #pragma unroll
        for (int cc = 0; cc < 8; ++cc) {
            int clin = q * 8 + cc;               // linear 8-elem chunk id
            int csw  = clin ^ (row & 7);         // swizzled chunk
            u16x8 v = {0, 0, 0, 0, 0, 0, 0, 0};
            if (smp >= 0) {
                const float4* p4 = (const float4*)(xr + cc * 8);
                float4 a0 = p4[0], a1 = p4[1];
                v[0] = f2bf(a0.x); v[1] = f2bf(a0.y); v[2] = f2bf(a0.z); v[3] = f2bf(a0.w);
                v[4] = f2bf(a1.x); v[5] = f2bf(a1.y); v[6] = f2bf(a1.z); v[7] = f2bf(a1.w);
            }
            *(u16x8*)&xs[row * 256 + (csw << 3)] = v;
        }
    }

    const unsigned short* w1e = w1T + (size_t)e * HID * INDIM;
    // stage K-slice ks into w1s[buf]: rows n (h), cols 32 k's. Linear LDS,
    // global_load_lds width=16; LDS dest wave-uniform base + lane*16.
    auto stage_w1 = [&](int buf, int ks) {
        #pragma unroll
        for (int i = 0; i < 4; ++i) {
            int nb = wave * 4 + i;                        // 16-row block
            const unsigned short* g = w1e
                + ((size_t)(nb * 16 + (lane >> 2))) * INDIM + ks * 32 + (lane & 3) * 8;
            unsigned short* l = &w1s[buf][nb * 16 * 32];  // wave-uniform
            gload_lds16(g, l);
        }
    };

    stage_w1(0, 0);
    __syncthreads();   // x staged + buf0 ready (sync drains vmcnt)

    f32x4 acc[4][4];
    #pragma unroll
    for (int mi = 0; mi < 4; ++mi)
        #pragma unroll
        for (int ni = 0; ni < 4; ++ni) {
            f32x4 z = {0.f, 0.f, 0.f, 0.f};
            acc[mi][ni] = z;
        }

    // Wave 'wave' owns output cols [wave*64, wave*64+64)
    #pragma unroll
    for (int ks = 0; ks < 8; ++ks) {
        int cur = ks & 1;
        if (ks < 7) stage_w1(cur ^ 1, ks + 1);
        bf16x8 af[4], bfr[4];
        #pragma unroll
        for (int mi = 0; mi < 4; ++mi) {
            int r  = mi * 16 + r15;                 // A row = lane&15 convention
            int cc = ks * 4 + hi;                   // k-chunk = (lane>>4)*8 .. +8
            af[mi] = *(const bf16x8*)&xs[r * 256 + ((cc ^ (r & 7)) << 3)];
        }
        #pragma unroll
        for (int ni = 0; ni < 4; ++ni) {
            int n = wave * 64 + ni * 16 + r15;      // B col = lane&15
            bfr[ni] = *(const bf16x8*)&w1s[cur][n * 32 + hi * 8];
        }
        #pragma unroll
        for (int mi = 0; mi < 4; ++mi)
            #pragma unroll
            for (int ni = 0; ni < 4; ++ni)
                acc[mi][ni] = __builtin_amdgcn_mfma_f32_16x16x32_bf16(
                    af[mi], bfr[ni], acc[mi][ni], 0, 0, 0);
        __syncthreads();   // readers done before next iter overwrites buffer
    }

    // ---- h = relu(acc + b1) -> xs (bf16, same swizzle) ----
    // D layout: col = lane&15, row = (lane>>4)*4 + j  [m89-verified]
    float b1v[4];
    #pragma unroll
    for (int ni = 0; ni < 4; ++ni)
        b1v[ni] = b1[e * HID + wave * 64 + ni * 16 + r15];
    #pragma unroll
    for (int mi = 0; mi < 4; ++mi) {
        #pragma unroll
        for (int ni = 0; ni < 4; ++ni) {
            int colg = wave * 64 + ni * 16 + r15;
            #pragma unroll
            for (int j = 0; j < 4; ++j) {
                int rowg = mi * 16 + hi * 4 + j;
                float h = fmaxf(acc[mi][ni][j] + b1v[ni], 0.f);
                xs[rowg * 256 + (((colg >> 3) ^ (rowg & 7)) << 3) + (colg & 7)] = f2bf(h);
            }
        }
    }
    __syncthreads();

    // ---- layer 2: logits[row][kk] = b2 + sum_i h[row][i] * W2[e][i][kk] ----
    int kk = tid & 3;                       // this thread's ordinal-logit index
    float accl = b2[e * KM1 + kk];
    const float* w2e = W2 + (size_t)e * HID * KM1;
    #pragma unroll 4
    for (int c = 0; c < 32; ++c) {
        u16x8 hv = *(const u16x8*)&xs[row * 256 + ((c ^ (row & 7)) << 3)];
        #pragma unroll
        for (int j = 0; j < 8; ++j)
            accl += bf2f(hv[j]) * w2e[(c * 8 + j) * KM1 + kk];
    }

    if (smp >= 0) {
        float qv    = 1.f / (1.f + expf(-accl));
        float qprev = __shfl_up(qv, 1, 4);
        float p  = (kk == 0) ? (1.f - qv) : (qprev - qv);
        p = fmaxf(p, 1e-8f);
        float p4 = fmaxf(qv, 1e-8f);                  // only meaningful at kk==3
        float s = p + ((kk == 3) ? p4 : 0.f);
        s += __shfl_xor(s, 1, 4);
        s += __shfl_xor(s, 2, 4);
        float inv = 1.f / s;
        out[(size_t)smp * KM1 + kk] = accl;           // logits
        float* probs = out + (size_t)B_N * KM1;
        probs[(size_t)smp * KCLS + kk] = p * inv;
        if (kk == 3) probs[(size_t)smp * KCLS + 4] = p4 * inv;
    }
}

extern "C" void kernel_launch(void* const* d_in, const int* in_sizes, int n_in,
                              void* d_out, int out_size, void* d_ws, size_t ws_size,
                              hipStream_t stream) {
    const float* x   = (const float*)d_in[0];
    const int*   sid = (const int*)d_in[1];
    const float* W1  = (const float*)d_in[2];
    const float* b1  = (const float*)d_in[3];
    const float* W2  = (const float*)d_in[4];
    const float* b2  = (const float*)d_in[5];
    float* out = (float*)d_out;

    // ws layout (needs ~1.2 MB)
    char* ws = (char*)d_ws;
    unsigned short* w1T = (unsigned short*)ws;             // 8*256*256*2 = 1048576 B
    int* perm   = (int*)(ws + 1048576);                    // 33280*4 = 133120 B
    int* hist   = (int*)(ws + 1048576 + 133120);           // 32 B
    int* cursor = (int*)(ws + 1048576 + 133152);           // 32 B
    int* offs   = (int*)(ws + 1048576 + 133184);           // 36 B

    k_w1t    <<<dim3(128),  dim3(256), 0, stream>>>(W1, w1T);
    k_init   <<<dim3(130),  dim3(256), 0, stream>>>(perm, hist);
    k_hist   <<<dim3(128),  dim3(256), 0, stream>>>(sid, hist);
    k_scan   <<<dim3(1),    dim3(64),  0, stream>>>(hist, offs, cursor);
    k_scatter<<<dim3(128),  dim3(256), 0, stream>>>(sid, cursor, perm);
    k_main   <<<dim3(NBLK), dim3(256), 0, stream>>>(x, b1, W2, b2, w1T, perm, offs, out);
}

// Round 2
// 49.617 us; speedup vs baseline: 3.4348x; 3.4348x over previous
//
#include <hip/hip_runtime.h>
#include <stdint.h>
#include <math.h>

// Problem constants (match reference)
#define B_N   32768
#define INDIM 256
#define HID   256
#define NE    8
#define KM1   4
#define KCLS  5
#define BM    64
#define PADN  (B_N + NE * BM)        // 33280: per-expert segments padded to 64
#define NBLK  (PADN / BM)            // 520

typedef __bf16 bf16x8 __attribute__((ext_vector_type(8)));
typedef float  f32x4  __attribute__((ext_vector_type(4)));
typedef unsigned short u16x8 __attribute__((ext_vector_type(8)));

__device__ __forceinline__ unsigned short f2bf(float f) {
    union { float f; unsigned u; } v; v.f = f;
    unsigned r = v.u + 0x7FFFu + ((v.u >> 16) & 1u);   // RNE
    return (unsigned short)(r >> 16);
}
__device__ __forceinline__ float bf2f(unsigned short b) {
    union { unsigned u; float f; } v; v.u = ((unsigned)b) << 16;
    return v.f;
}

// ---- prep: W1 [E][IN][HID] f32  ->  w1T [E][HID][IN] bf16 (transposed) ----
__global__ __launch_bounds__(256) void k_w1t(const float* __restrict__ W1,
                                             unsigned short* __restrict__ w1T) {
    __shared__ float tile[64][65];
    int b  = blockIdx.x;            // E*4*4 = 128 blocks
    int e  = b >> 4;
    int ti = (b >> 2) & 3;          // i (K) tile
    int th = b & 3;                 // h (N) tile
    const float* src = W1 + (((size_t)e * INDIM) + (size_t)ti * 64) * HID + th * 64;
    int col = threadIdx.x & 63;
    int r0  = (threadIdx.x >> 6) * 16;
    #pragma unroll
    for (int rr = 0; rr < 16; ++rr)
        tile[r0 + rr][col] = src[(size_t)(r0 + rr) * HID + col];
    __syncthreads();
    int hl = threadIdx.x >> 2;      // 0..63  (h within tile)
    int iq = threadIdx.x & 3;       // quarter of i range
    unsigned short* dst = w1T + (((size_t)e * HID) + th * 64 + hl) * INDIM + ti * 64 + iq * 16;
    #pragma unroll
    for (int s = 0; s < 16; ++s)
        dst[s] = f2bf(tile[iq * 16 + s][hl]);
}

// ---- prep: init perm = -1, hist = 0 ----
__global__ void k_init(int* __restrict__ perm, int* __restrict__ hist) {
    int i = blockIdx.x * 256 + threadIdx.x;
    if (i < PADN) perm[i] = -1;
    if (i < NE && blockIdx.x == 0) hist[i] = 0;
}

// ---- prep: histogram of experts ----
__global__ void k_hist(const int* __restrict__ sidx, int* __restrict__ hist) {
    __shared__ int lh[NE];
    if (threadIdx.x < NE) lh[threadIdx.x] = 0;
    __syncthreads();
    int i = blockIdx.x * 256 + threadIdx.x;
    if (i < B_N) atomicAdd(&lh[sidx[i]], 1);
    __syncthreads();
    if (threadIdx.x < NE) atomicAdd(&hist[threadIdx.x], lh[threadIdx.x]);
}

// ---- prep: exclusive scan with 64-row padding; init cursors ----
__global__ void k_scan(const int* __restrict__ hist, int* __restrict__ offs,
                       int* __restrict__ cursor) {
    if (threadIdx.x == 0) {
        int acc = 0;
        for (int e = 0; e < NE; ++e) {
            offs[e] = acc;
            cursor[e] = acc;
            acc += ((hist[e] + BM - 1) / BM) * BM;
        }
        offs[NE] = acc;
    }
}

// ---- prep: scatter sample ids into per-expert segments ----
// Block-aggregated to avoid same-address global-atomic serialization:
// per-block LDS histogram -> 8 global atomics per block -> local offsets.
__global__ __launch_bounds__(256) void k_scatter(const int* __restrict__ sidx,
                                                 int* __restrict__ cursor,
                                                 int* __restrict__ perm) {
    __shared__ int lh[NE];
    __shared__ int base[NE];
    if (threadIdx.x < NE) lh[threadIdx.x] = 0;
    __syncthreads();
    int i = blockIdx.x * 256 + threadIdx.x;
    int e = 0, pos = 0;
    if (i < B_N) {
        e = sidx[i];
        pos = atomicAdd(&lh[e], 1);          // LDS atomic: cheap
    }
    __syncthreads();
    if (threadIdx.x < NE)
        base[threadIdx.x] = atomicAdd(&cursor[threadIdx.x], lh[threadIdx.x]);
    __syncthreads();
    if (i < B_N)
        perm[base[e] + pos] = i;
}

__device__ __forceinline__ void gload_lds16(const void* g, void* l) {
    __builtin_amdgcn_global_load_lds(
        (__attribute__((address_space(1))) unsigned int*)(g),
        (__attribute__((address_space(3))) unsigned int*)(l),
        16, 0, 0);
}

// ---- main: fused grouped GEMM (bf16 MFMA) + bias/relu + layer2 + ordinal probs ----
__global__ __launch_bounds__(256) void k_main(
    const float* __restrict__ x,  const float* __restrict__ b1,
    const float* __restrict__ W2, const float* __restrict__ b2,
    const unsigned short* __restrict__ w1T,
    const int* __restrict__ perm, const int* __restrict__ offs,
    float* __restrict__ out)
{
    // xs: 64 rows x 256 bf16, 16B-chunk XOR-swizzled (chunk ^= row&7). 32KB.
    // Reused for h after the K loop.
    __shared__ unsigned short xs[BM * 256];
    // W1 K-slice staging, [n=256][k=32] bf16, double buffered. 2x16KB.
    __shared__ unsigned short w1s[2][256 * 32];

    int base = blockIdx.x * BM;
    if (base >= offs[NE]) return;
    int e = 0;
    #pragma unroll
    for (int t = 1; t < NE; ++t) if (base >= offs[t]) e = t;

    int tid  = threadIdx.x;
    int lane = tid & 63;
    int wave = tid >> 6;
    int r15  = lane & 15;
    int hi   = lane >> 4;

    // ---- stage gathered x rows -> LDS bf16 (swizzled) ----
    int row = tid >> 2;          // 0..63: local row
    int q   = tid & 3;           // quarter of the 256 cols
    int smp = perm[base + row];
    {
        const float* xr = x + (size_t)(smp < 0 ? 0 : smp) * INDIM + q * 64;
        #pragma unroll
        for (int cc = 0; cc < 8; ++cc) {
            int clin = q * 8 + cc;               // linear 8-elem chunk id
            int csw  = clin ^ (row & 7);         // swizzled chunk
            u16x8 v = {0, 0, 0, 0, 0, 0, 0, 0};
            if (smp >= 0) {
                const float4* p4 = (const float4*)(xr + cc * 8);
                float4 a0 = p4[0], a1 = p4[1];
                v[0] = f2bf(a0.x); v[1] = f2bf(a0.y); v[2] = f2bf(a0.z); v[3] = f2bf(a0.w);
                v[4] = f2bf(a1.x); v[5] = f2bf(a1.y); v[6] = f2bf(a1.z); v[7] = f2bf(a1.w);
            }
            *(u16x8*)&xs[row * 256 + (csw << 3)] = v;
        }
    }

    const unsigned short* w1e = w1T + (size_t)e * HID * INDIM;
    // stage K-slice ks into w1s[buf]: rows n (h), cols 32 k's. Linear LDS,
    // global_load_lds width=16; LDS dest wave-uniform base + lane*16.
    auto stage_w1 = [&](int buf, int ks) {
        #pragma unroll
        for (int i = 0; i < 4; ++i) {
            int nb = wave * 4 + i;                        // 16-row block
            const unsigned short* g = w1e
                + ((size_t)(nb * 16 + (lane >> 2))) * INDIM + ks * 32 + (lane & 3) * 8;
            unsigned short* l = &w1s[buf][nb * 16 * 32];  // wave-uniform
            gload_lds16(g, l);
        }
    };

    stage_w1(0, 0);
    __syncthreads();   // x staged + buf0 ready (sync drains vmcnt)

    f32x4 acc[4][4];
    #pragma unroll
    for (int mi = 0; mi < 4; ++mi)
        #pragma unroll
        for (int ni = 0; ni < 4; ++ni) {
            f32x4 z = {0.f, 0.f, 0.f, 0.f};
            acc[mi][ni] = z;
        }

    // Wave 'wave' owns output cols [wave*64, wave*64+64)
    #pragma unroll
    for (int ks = 0; ks < 8; ++ks) {
        int cur = ks & 1;
        if (ks < 7) stage_w1(cur ^ 1, ks + 1);
        bf16x8 af[4], bfr[4];
        #pragma unroll
        for (int mi = 0; mi < 4; ++mi) {
            int r  = mi * 16 + r15;                 // A row = lane&15 convention
            int cc = ks * 4 + hi;                   // k-chunk = (lane>>4)*8 .. +8
            af[mi] = *(const bf16x8*)&xs[r * 256 + ((cc ^ (r & 7)) << 3)];
        }
        #pragma unroll
        for (int ni = 0; ni < 4; ++ni) {
            int n = wave * 64 + ni * 16 + r15;      // B col = lane&15
            bfr[ni] = *(const bf16x8*)&w1s[cur][n * 32 + hi * 8];
        }
        #pragma unroll
        for (int mi = 0; mi < 4; ++mi)
            #pragma unroll
            for (int ni = 0; ni < 4; ++ni)
                acc[mi][ni] = __builtin_amdgcn_mfma_f32_16x16x32_bf16(
                    af[mi], bfr[ni], acc[mi][ni], 0, 0, 0);
        __syncthreads();   // readers done before next iter overwrites buffer
    }

    // ---- h = relu(acc + b1) -> xs (bf16, same swizzle) ----
    // D layout: col = lane&15, row = (lane>>4)*4 + j  [m89-verified]
    float b1v[4];
    #pragma unroll
    for (int ni = 0; ni < 4; ++ni)
        b1v[ni] = b1[e * HID + wave * 64 + ni * 16 + r15];
    #pragma unroll
    for (int mi = 0; mi < 4; ++mi) {
        #pragma unroll
        for (int ni = 0; ni < 4; ++ni) {
            int colg = wave * 64 + ni * 16 + r15;
            #pragma unroll
            for (int j = 0; j < 4; ++j) {
                int rowg = mi * 16 + hi * 4 + j;
                float h = fmaxf(acc[mi][ni][j] + b1v[ni], 0.f);
                xs[rowg * 256 + (((colg >> 3) ^ (rowg & 7)) << 3) + (colg & 7)] = f2bf(h);
            }
        }
    }
    __syncthreads();

    // ---- layer 2: logits[row][kk] = b2 + sum_i h[row][i] * W2[e][i][kk] ----
    int kk = tid & 3;                       // this thread's ordinal-logit index
    float accl = b2[e * KM1 + kk];
    const float* w2e = W2 + (size_t)e * HID * KM1;
    #pragma unroll 4
    for (int c = 0; c < 32; ++c) {
        u16x8 hv = *(const u16x8*)&xs[row * 256 + ((c ^ (row & 7)) << 3)];
        #pragma unroll
        for (int j = 0; j < 8; ++j)
            accl += bf2f(hv[j]) * w2e[(c * 8 + j) * KM1 + kk];
    }

    if (smp >= 0) {
        float qv    = 1.f / (1.f + expf(-accl));
        float qprev = __shfl_up(qv, 1, 4);
        float p  = (kk == 0) ? (1.f - qv) : (qprev - qv);
        p = fmaxf(p, 1e-8f);
        float p4 = fmaxf(qv, 1e-8f);                  // only meaningful at kk==3
        float s = p + ((kk == 3) ? p4 : 0.f);
        s += __shfl_xor(s, 1, 4);
        s += __shfl_xor(s, 2, 4);
        float inv = 1.f / s;
        out[(size_t)smp * KM1 + kk] = accl;           // logits
        float* probs = out + (size_t)B_N * KM1;
        probs[(size_t)smp * KCLS + kk] = p * inv;
        if (kk == 3) probs[(size_t)smp * KCLS + 4] = p4 * inv;
    }
}

extern "C" void kernel_launch(void* const* d_in, const int* in_sizes, int n_in,
                              void* d_out, int out_size, void* d_ws, size_t ws_size,
                              hipStream_t stream) {
    const float* x   = (const float*)d_in[0];
    const int*   sid = (const int*)d_in[1];
    const float* W1  = (const float*)d_in[2];
    const float* b1  = (const float*)d_in[3];
    const float* W2  = (const float*)d_in[4];
    const float* b2  = (const float*)d_in[5];
    float* out = (float*)d_out;

    // ws layout (needs ~1.2 MB)
    char* ws = (char*)d_ws;
    unsigned short* w1T = (unsigned short*)ws;             // 8*256*256*2 = 1048576 B
    int* perm   = (int*)(ws + 1048576);                    // 33280*4 = 133120 B
    int* hist   = (int*)(ws + 1048576 + 133120);           // 32 B
    int* cursor = (int*)(ws + 1048576 + 133152);           // 32 B
    int* offs   = (int*)(ws + 1048576 + 133184);           // 36 B

    k_w1t    <<<dim3(128),  dim3(256), 0, stream>>>(W1, w1T);
    k_init   <<<dim3(130),  dim3(256), 0, stream>>>(perm, hist);
    k_hist   <<<dim3(128),  dim3(256), 0, stream>>>(sid, hist);
    k_scan   <<<dim3(1),    dim3(64),  0, stream>>>(hist, offs, cursor);
    k_scatter<<<dim3(128),  dim3(256), 0, stream>>>(sid, cursor, perm);
    k_main   <<<dim3(NBLK), dim3(256), 0, stream>>>(x, b1, W2, b2, w1T, perm, offs, out);
}